// Round 6
// baseline (54.964 us; speedup 1.0000x reference)
//
#include <hip/hip_runtime.h>

typedef float f32x2 __attribute__((ext_vector_type(2)));
typedef float f32x4 __attribute__((ext_vector_type(4)));
typedef _Float16 h16x2 __attribute__((ext_vector_type(2)));

#define HH 128
#define WW 192
#define HO 256
#define WO 384
#define NINST 256
#define OTY 16          // output rows per block
#define LTY 10          // low-res rows staged
#define LPAD 196        // tile row pitch in floats (784B, 16B aligned)
#define STRIPS 24       // 192/8 strips per low-res row
#define PSTRIDE 170     // f16 param row stride (even -> dword-aligned rows)
#define WS_NEED (NINST * PSTRIDE * 2)

static __device__ __forceinline__ unsigned pkrtz(float a, float b) {
    return __builtin_bit_cast(unsigned, __builtin_amdgcn_cvt_pkrtz(a, b));
}

static __device__ __forceinline__ float dot2(unsigned a, unsigned b, float c) {
#if __has_builtin(__builtin_amdgcn_fdot2)
    return __builtin_amdgcn_fdot2(__builtin_bit_cast(h16x2, a),
                                  __builtin_bit_cast(h16x2, b), c, false);
#else
    h16x2 x = __builtin_bit_cast(h16x2, a), y = __builtin_bit_cast(h16x2, b);
    return fmaf((float)x[1], (float)y[1], fmaf((float)x[0], (float)y[0], c));
#endif
}

// ---- pre-kernel: params f32 -> f16 table (row stride 170 for alignment) ----
__global__ __launch_bounds__(256) void prep_params(const float* __restrict__ p,
                                                   unsigned short* __restrict__ o16) {
    int j = blockIdx.x * 256 + threadIdx.x;          // 0..43263
    if (j < NINST * 169) {
        int n = j / 169, k = j - n * 169;
        _Float16 h = (_Float16)p[j];                  // round-to-nearest
        o16[n * PSTRIDE + k] = __builtin_bit_cast(unsigned short, h);
    }
}

// ---- main fused kernel: f16-dot2 MLP + f32 bilinear upsample ----
__global__ __launch_bounds__(256) void dynmask_fused(
    const float* __restrict__ feats,    // (2, 8, 128, 192)
    const float* __restrict__ params,   // (256, 169) f32 (biases, coord weights)
    const unsigned short* __restrict__ params16, // (256, 170) f16
    const float* __restrict__ locs,
    const float* __restrict__ soi,
    const int*   __restrict__ im_inds,
    const int*   __restrict__ stride_p,
    float* __restrict__ out)            // (256, 1, 256, 384)
{
    const int n   = blockIdx.y;
    const int t   = threadIdx.x;
    const int oy0 = blockIdx.x * OTY;

    __shared__ float tile[LTY][LPAD];

    const float sy = 127.0f / 255.0f;
    const float sx = 191.0f / 383.0f;
    const int ly0 = (int)((float)oy0 * sy);

    // wave-uniform -> SGPRs / s_loads
    const float* __restrict__ pw = params + n * 169;
    const unsigned short* __restrict__ pw16 = params16 + n * PSTRIDE;
    const int   stride  = *stride_p;
    const float inv_soi = 1.0f / soi[n];
    const float loc_x   = locs[2*n+0];
    const float loc_y   = locs[2*n+1];
    const float* fbase  = feats + im_inds[n] * (8*HH*WW);
    const float xstep   = -(float)stride * inv_soi;

    #define W0P(o,kp) (*(const unsigned*)(pw16 + (o)*10 + 2 + 2*(kp)))
    #define W1P(o,kp) (*(const unsigned*)(pw16 + 80 + (o)*8 + 2*(kp)))
    #define W2P(kp)   (*(const unsigned*)(pw16 + 144 + 2*(kp)))

    if (t < LTY * STRIPS) {
        const int r  = (unsigned)t / STRIPS;          // 0..9
        const int c0 = (t - r*STRIPS) * 8;
        int gy = ly0 + r; if (gy > HH-1) gy = HH-1;
        const float* frow = fbase + gy*WW + c0;

        const float yrel = (loc_y - (float)(gy*stride + (stride>>1))) * inv_soi;
        const float xr0  = (loc_x - (float)(c0*stride + (stride>>1))) * inv_soi;

        float wxw[8], byo[8];
        #pragma unroll
        for (int o = 0; o < 8; ++o) {
            wxw[o] = pw[o*10+0];
            byo[o] = fmaf(yrel, pw[o*10+1], pw[152+o]);   // y-term hoisted
        }

        #pragma unroll
        for (int g = 0; g < 2; ++g) {
            f32x4 f[8];
            #pragma unroll
            for (int ch = 0; ch < 8; ++ch)
                f[ch] = *(const f32x4*)(frow + ch*(HH*WW) + g*4);

            float xr[4];
            #pragma unroll
            for (int j = 0; j < 4; ++j)
                xr[j] = fmaf((float)(g*4+j), xstep, xr0);

            // pack feature channel-pairs to f16x2: fp[chp][px]
            unsigned fp[4][4];
            #pragma unroll
            for (int cp = 0; cp < 4; ++cp)
                #pragma unroll
                for (int j = 0; j < 4; ++j)
                    fp[cp][j] = pkrtz(f[2*cp][j], f[2*cp+1][j]);

            // layer 0: 10 -> 8, relu. coords in f32, feats via dot2, f32 accum
            float h0[4][8];
            #pragma unroll
            for (int o = 0; o < 8; ++o) {
                #pragma unroll
                for (int j = 0; j < 4; ++j) {
                    float a = fmaf(xr[j], wxw[o], byo[o]);
                    a = dot2(fp[0][j], W0P(o,0), a);
                    a = dot2(fp[1][j], W0P(o,1), a);
                    a = dot2(fp[2][j], W0P(o,2), a);
                    a = dot2(fp[3][j], W0P(o,3), a);
                    h0[j][o] = fmaxf(a, 0.0f);
                }
            }

            unsigned hp[4][4];
            #pragma unroll
            for (int j = 0; j < 4; ++j)
                #pragma unroll
                for (int cp = 0; cp < 4; ++cp)
                    hp[j][cp] = pkrtz(h0[j][2*cp], h0[j][2*cp+1]);

            // layer 1: 8 -> 8, relu
            float h1[4][8];
            #pragma unroll
            for (int o = 0; o < 8; ++o) {
                #pragma unroll
                for (int j = 0; j < 4; ++j) {
                    float a = pw[160+o];
                    a = dot2(hp[j][0], W1P(o,0), a);
                    a = dot2(hp[j][1], W1P(o,1), a);
                    a = dot2(hp[j][2], W1P(o,2), a);
                    a = dot2(hp[j][3], W1P(o,3), a);
                    h1[j][o] = fmaxf(a, 0.0f);
                }
            }

            // layer 2: 8 -> 1
            f32x4 rv;
            #pragma unroll
            for (int j = 0; j < 4; ++j) {
                unsigned p0 = pkrtz(h1[j][0], h1[j][1]);
                unsigned p1 = pkrtz(h1[j][2], h1[j][3]);
                unsigned p2 = pkrtz(h1[j][4], h1[j][5]);
                unsigned p3 = pkrtz(h1[j][6], h1[j][7]);
                float a = pw[168];
                a = dot2(p0, W2P(0), a);
                a = dot2(p1, W2P(1), a);
                a = dot2(p2, W2P(2), a);
                a = dot2(p3, W2P(3), a);
                rv[j] = a;
            }
            *(f32x4*)&tile[r][c0 + g*4] = rv;
        }
    }

    __syncthreads();

    // ---- upsample: 3 units/thread, unit = (one column, 8 rows) ----
    float* obase = out + (size_t)n * (HO*WO);
    #pragma unroll
    for (int k = 0; k < 3; ++k) {
        const int u    = t + k*256;
        const int wrap = (u >= 384);
        const int col  = wrap ? u - 384 : u;
        const int r0o  = wrap ? 8 : 0;

        const float xsf = (float)col * sx;
        int ix0 = (int)xsf; if (ix0 > WW-2) ix0 = WW-2;
        const float wx = xsf - (float)ix0;
        const float* tcol = &tile[0][0] + ix0;

        float a, b, c, d;
        int prevIy = -999;
        float* optr = obase + (size_t)(oy0 + r0o) * WO + col;

        for (int rr = 0; rr < 8; ++rr) {
            const int   yo  = oy0 + r0o + rr;
            const float ysf = (float)yo * sy;
            int iy0 = (int)ysf; if (iy0 > HH-2) iy0 = HH-2;
            const float wy = ysf - (float)iy0;

            if (iy0 != prevIy) {
                const float* p = tcol + (iy0 - ly0) * LPAD;
                if (iy0 == prevIy + 1) {
                    a = c; b = d;
                    c = p[LPAD]; d = p[LPAD+1];
                } else {
                    a = p[0];    b = p[1];
                    c = p[LPAD]; d = p[LPAD+1];
                }
                prevIy = iy0;
            }

            float va = fmaf(wy, c - a, a);
            float vb = fmaf(wy, d - b, b);
            *optr = fmaf(wx, vb - va, va);
            optr += WO;
        }
    }
    #undef W0P
    #undef W1P
    #undef W2P
}

// ---- fallback (round-5 f32 kernel) if workspace is too small ----
__global__ __launch_bounds__(256) void dynmask_fused_f32(
    const float* __restrict__ feats,
    const float* __restrict__ params,
    const float* __restrict__ locs,
    const float* __restrict__ soi,
    const int*   __restrict__ im_inds,
    const int*   __restrict__ stride_p,
    float* __restrict__ out)
{
    const int n   = blockIdx.y;
    const int t   = threadIdx.x;
    const int oy0 = blockIdx.x * OTY;

    __shared__ float tile[LTY][LPAD];

    const float sy = 127.0f / 255.0f;
    const float sx = 191.0f / 383.0f;
    const int ly0 = (int)((float)oy0 * sy);

    const float* __restrict__ pw = params + n * 169;
    const int   stride  = *stride_p;
    const float inv_soi = 1.0f / soi[n];
    const float loc_x   = locs[2*n+0];
    const float loc_y   = locs[2*n+1];
    const float* fbase  = feats + im_inds[n] * (8*HH*WW);
    const float xstep   = -(float)stride * inv_soi;

    if (t < LTY * STRIPS) {
        const int r  = (unsigned)t / STRIPS;
        const int c0 = (t - r*STRIPS) * 8;
        int gy = ly0 + r; if (gy > HH-1) gy = HH-1;
        const float* frow = fbase + gy*WW + c0;

        const float yrel = (loc_y - (float)(gy*stride + (stride>>1))) * inv_soi;
        const float xr0  = (loc_x - (float)(c0*stride + (stride>>1))) * inv_soi;

        #pragma unroll
        for (int g = 0; g < 2; ++g) {
            f32x4 f[8];
            #pragma unroll
            for (int ch = 0; ch < 8; ++ch)
                f[ch] = *(const f32x4*)(frow + ch*(HH*WW) + g*4);

            float xr[4];
            #pragma unroll
            for (int j = 0; j < 4; ++j)
                xr[j] = fmaf((float)(g*4+j), xstep, xr0);

            float h0[4][8];
            #pragma unroll
            for (int o = 0; o < 8; ++o) {
                const float byo = fmaf(yrel, pw[o*10+1], pw[152+o]);
                const float wxw = pw[o*10+0];
                #pragma unroll
                for (int j = 0; j < 4; ++j) {
                    float a = fmaf(xr[j], wxw, byo);
                    #pragma unroll
                    for (int ch = 0; ch < 8; ++ch)
                        a = fmaf(f[ch][j], pw[o*10+2+ch], a);
                    h0[j][o] = fmaxf(a, 0.0f);
                }
            }

            f32x4 rv;
            #pragma unroll
            for (int j = 0; j < 4; ++j) rv[j] = pw[168];
            #pragma unroll
            for (int o = 0; o < 8; ++o) {
                const float b1w = pw[160+o];
                const float w2w = pw[144+o];
                #pragma unroll
                for (int j = 0; j < 4; ++j) {
                    float a = b1w;
                    #pragma unroll
                    for (int c = 0; c < 8; ++c)
                        a = fmaf(h0[j][c], pw[80+o*8+c], a);
                    rv[j] = fmaf(fmaxf(a, 0.0f), w2w, rv[j]);
                }
            }
            *(f32x4*)&tile[r][c0 + g*4] = rv;
        }
    }

    __syncthreads();

    float* obase = out + (size_t)n * (HO*WO);
    #pragma unroll
    for (int k = 0; k < 3; ++k) {
        const int u    = t + k*256;
        const int wrap = (u >= 384);
        const int col  = wrap ? u - 384 : u;
        const int r0o  = wrap ? 8 : 0;

        const float xsf = (float)col * sx;
        int ix0 = (int)xsf; if (ix0 > WW-2) ix0 = WW-2;
        const float wx = xsf - (float)ix0;
        const float* tcol = &tile[0][0] + ix0;

        float a, b, c, d;
        int prevIy = -999;
        float* optr = obase + (size_t)(oy0 + r0o) * WO + col;

        for (int rr = 0; rr < 8; ++rr) {
            const int   yo  = oy0 + r0o + rr;
            const float ysf = (float)yo * sy;
            int iy0 = (int)ysf; if (iy0 > HH-2) iy0 = HH-2;
            const float wy = ysf - (float)iy0;

            if (iy0 != prevIy) {
                const float* p = tcol + (iy0 - ly0) * LPAD;
                if (iy0 == prevIy + 1) {
                    a = c; b = d;
                    c = p[LPAD]; d = p[LPAD+1];
                } else {
                    a = p[0];    b = p[1];
                    c = p[LPAD]; d = p[LPAD+1];
                }
                prevIy = iy0;
            }

            float va = fmaf(wy, c - a, a);
            float vb = fmaf(wy, d - b, b);
            *optr = fmaf(wx, vb - va, va);
            optr += WO;
        }
    }
}

extern "C" void kernel_launch(void* const* d_in, const int* in_sizes, int n_in,
                              void* d_out, int out_size, void* d_ws, size_t ws_size,
                              hipStream_t stream) {
    const float* feats    = (const float*)d_in[0];
    const float* params   = (const float*)d_in[1];
    const float* locs     = (const float*)d_in[2];
    const float* soi      = (const float*)d_in[3];
    const int*   im_inds  = (const int*)d_in[4];
    const int*   stride_p = (const int*)d_in[6];
    float* out = (float*)d_out;

    dim3 grid(HO / OTY, NINST);   // (16, 256)
    dim3 block(256);

    if (ws_size >= (size_t)WS_NEED) {
        unsigned short* params16 = (unsigned short*)d_ws;
        hipLaunchKernelGGL(prep_params, dim3(170), dim3(256), 0, stream,
                           params, params16);
        hipLaunchKernelGGL(dynmask_fused, grid, block, 0, stream,
                           feats, params, params16, locs, soi, im_inds, stride_p, out);
    } else {
        hipLaunchKernelGGL(dynmask_fused_f32, grid, block, 0, stream,
                           feats, params, locs, soi, im_inds, stride_p, out);
    }
}